// Round 2
// baseline (176.025 us; speedup 1.0000x reference)
//
#include <hip/hip_runtime.h>
#include <hip/hip_bf16.h>

#define S_LEN 8192
#define HID 768
#define NH 12
#define HD 64
#define WIN 256

typedef __bf16 bf16x8 __attribute__((ext_vector_type(8)));
typedef float f32x4 __attribute__((ext_vector_type(4)));
using bf16_t = __hip_bfloat16;

#define MFMA(a, b, c) __builtin_amdgcn_mfma_f32_16x16x32_bf16(a, b, c, 0, 0, 0)

// async global->LDS, 16B/lane; LDS dest is wave-uniform base (+lane*16 in HW)
__device__ __forceinline__ void gl2lds16(const bf16_t* g, bf16_t* l) {
  __builtin_amdgcn_global_load_lds(
      (const __attribute__((address_space(1))) void*)g,
      (__attribute__((address_space(3))) void*)l, 16, 0, 0);
}

// ---- prep: fused hs fp32->bf16 convert + weight transpose ---------------
// blocks [0, 6144): convert; blocks [6144, 7872): transpose (24x24x3).
__global__ __launch_bounds__(256) void prep(const float* __restrict__ hs,
                                            bf16_t* __restrict__ hb,
                                            const float* __restrict__ Wq,
                                            const float* __restrict__ Wk,
                                            const float* __restrict__ Wv,
                                            bf16_t* __restrict__ Wt) {
  int bx = blockIdx.x;
  int tid = threadIdx.x;
  if (bx < 6144) {
    int i = (bx * 256 + tid) * 4;
    float4 v = *reinterpret_cast<const float4*>(hs + i);
    union { ushort4 u; bf16_t b[4]; } H;
    H.b[0] = __float2bfloat16(v.x);
    H.b[1] = __float2bfloat16(v.y);
    H.b[2] = __float2bfloat16(v.z);
    H.b[3] = __float2bfloat16(v.w);
    *reinterpret_cast<ushort4*>(hb + i) = H.u;
    return;
  }
  __shared__ float t[32][33];
  int b = bx - 6144;
  int z = b / 576;
  int r = b % 576;
  int n0 = (r / 24) * 32, k0 = (r % 24) * 32;
  const float* src = (z == 0) ? Wq : ((z == 1) ? Wk : Wv);
  int tx = tid & 31, ty = tid >> 5;  // 32 x 8
  for (int i = 0; i < 4; ++i)
    t[ty + i * 8][tx] = src[(k0 + ty + i * 8) * HID + n0 + tx];
  __syncthreads();
  bf16_t* dst = Wt + z * HID * HID;
  for (int i = 0; i < 4; ++i)
    dst[(n0 + ty + i * 8) * HID + k0 + tx] = __float2bfloat16(t[tx][ty + i * 8]);
}

// ---- fused QKV GEMM, R7: 8-phase-style schedule (T3+T4+T5) --------------
// 128x256 tile, BK=64, 8 waves (2M x 4N), 3-deep LDS pipeline (144KB).
// Per K-tile: 2 phases x {8 ds_read_b128 | stage-issue | bar | 16 MFMA | bar},
// counted s_waitcnt vmcnt(6) ONCE per K-tile (tile t+2 stays in flight).
// N-tiles of 256 align with Q/K/V boundaries (768 = 3*256) -> zq swap kept.
__global__ __launch_bounds__(512, 2) void qkv_gemm(
    const bf16_t* __restrict__ hb, const bf16_t* __restrict__ Wt,
    const float* __restrict__ bq, const float* __restrict__ bk,
    const float* __restrict__ bv,
    bf16_t* __restrict__ Qw, bf16_t* __restrict__ Kw, bf16_t* __restrict__ Vt) {
  __shared__ __align__(16) bf16_t sA[3][128 * 64];  // 48KB
  __shared__ __align__(16) bf16_t sB[3][256 * 64];  // 96KB
  int m0 = blockIdx.x * 128;
  int zq = blockIdx.y / 3;
  int nn0 = (blockIdx.y % 3) * 256;
  int n0g = zq * HID + nn0;
  int tid = threadIdx.x;
  int w = tid >> 6, lane = tid & 63, lm = lane & 15, qd = lane >> 4;
  int wm = w >> 2, wn = w & 3;  // 2M x 4N waves, 64x64 out each

  int srow = w * 8 + (lane >> 3);                 // [0,64)
  int sc8 = (lane & 7) ^ ((lane >> 3) & 7);       // XOR-8 chunk swizzle
  const bf16_t* gA = hb + (m0 + srow) * HID + sc8 * 8;
  const bf16_t* gB = Wt + (n0g + srow) * HID + sc8 * 8;
  int sx0 = lm & 7;

  // per wave: 2 A-load + 4 B-load instructions per K-tile (vmcnt units)
#define STAGE_A(kk, bb)                                      \
  {                                                          \
    gl2lds16(gA + (kk), &sA[bb][w * 512]);                   \
    gl2lds16(gA + 64 * HID + (kk), &sA[bb][4096 + w * 512]); \
  }
#define STAGE_B(kk, bb)                                        \
  {                                                            \
    gl2lds16(gB + (kk), &sB[bb][w * 512]);                     \
    gl2lds16(gB + 64 * HID + (kk), &sB[bb][4096 + w * 512]);   \
    gl2lds16(gB + 128 * HID + (kk), &sB[bb][8192 + w * 512]);  \
    gl2lds16(gB + 192 * HID + (kk), &sB[bb][12288 + w * 512]); \
  }

#define PHASE_MFMA(FA, FB)                                \
  __builtin_amdgcn_s_setprio(1);                          \
  if (zq == 2) {                                          \
    _Pragma("unroll") for (int i = 0; i < 4; ++i)         \
        _Pragma("unroll") for (int j = 0; j < 4; ++j)     \
            acc[i][j] = MFMA(FB[i], FA[j], acc[i][j]);    \
  } else {                                                \
    _Pragma("unroll") for (int i = 0; i < 4; ++i)         \
        _Pragma("unroll") for (int j = 0; j < 4; ++j)     \
            acc[i][j] = MFMA(FA[i], FB[j], acc[i][j]);    \
  }                                                       \
  __builtin_amdgcn_s_setprio(0);

  // prologue: stage tiles 0 and 1; retire tile 0 (FIFO -> vmcnt(6))
  STAGE_A(0, 0); STAGE_B(0, 0);
  STAGE_A(64, 1); STAGE_B(64, 1);
  asm volatile("s_waitcnt vmcnt(6)" ::: "memory");
  __builtin_amdgcn_s_barrier();

  f32x4 acc[4][4] = {};
  for (int t = 0; t < 12; ++t) {
    const bf16_t* a_c = sA[t % 3];
    const bf16_t* b_c = sB[t % 3];
    int nb = (t + 2) % 3;     // buffer for tile t+2 (== buf[(t-1)%3])
    int kk2 = (t + 2) * 64;
    // ---- phase 0: K-half 0 ------------------------------------------
    {
      bf16x8 fa[4], fb[4];
      int ca = qd ^ sx0;
#pragma unroll
      for (int i = 0; i < 4; ++i) {
        fa[i] = *reinterpret_cast<const bf16x8*>(
            a_c + (wm * 64 + i * 16 + lm) * 64 + ca * 8);
        fb[i] = *reinterpret_cast<const bf16x8*>(
            b_c + (wn * 64 + i * 16 + lm) * 64 + ca * 8);
      }
      if (t < 10) STAGE_A(kk2, nb);
      __builtin_amdgcn_s_barrier();
      PHASE_MFMA(fa, fb);
      __builtin_amdgcn_s_barrier();
    }
    // ---- phase 1: K-half 1 ------------------------------------------
    {
      bf16x8 fa[4], fb[4];
      int ca = (qd + 4) ^ sx0;
#pragma unroll
      for (int i = 0; i < 4; ++i) {
        fa[i] = *reinterpret_cast<const bf16x8*>(
            a_c + (wm * 64 + i * 16 + lm) * 64 + ca * 8);
        fb[i] = *reinterpret_cast<const bf16x8*>(
            b_c + (wn * 64 + i * 16 + lm) * 64 + ca * 8);
      }
      if (t < 10) STAGE_B(kk2, nb);
      __builtin_amdgcn_s_barrier();
      PHASE_MFMA(fa, fb);
      // retire tile t+1's 6 loads (oldest in FIFO); keep t+2's in flight
      if (t < 10) {
        asm volatile("s_waitcnt vmcnt(6)" ::: "memory");
      } else if (t < 11) {
        asm volatile("s_waitcnt vmcnt(0)" ::: "memory");
      }
      __builtin_amdgcn_s_barrier();
    }
  }

  if (zq != 2) {
    const float* bias = zq ? bk : bq;
    bf16_t* dst = zq ? Kw : Qw;
    float scale = zq ? 1.0f : 0.125f;  // fold 1/sqrt(D) into Q
#pragma unroll
    for (int j = 0; j < 4; ++j) {
      int nl = nn0 + wn * 64 + j * 16 + lm;
      float bb = bias[nl];
      int h = nl >> 6, d = nl & 63;
#pragma unroll
      for (int i = 0; i < 4; ++i)
#pragma unroll
        for (int r = 0; r < 4; ++r) {
          int m = m0 + wm * 64 + i * 16 + qd * 4 + r;
          dst[(h * S_LEN + m) * HD + d] =
              __float2bfloat16((acc[i][j][r] + bb) * scale);
        }
    }
  } else {
#pragma unroll
    for (int i = 0; i < 4; ++i)
#pragma unroll
      for (int r = 0; r < 4; ++r) {
        int nl = nn0 + wn * 64 + i * 16 + qd * 4 + r;  // nl == h*64+d
        float bb = bv[nl];
#pragma unroll
        for (int j = 0; j < 4; ++j) {
          int m = m0 + wm * 64 + j * 16 + lm;
          Vt[nl * S_LEN + m] = __float2bfloat16(acc[i][j][r] + bb);
        }
      }
  }
}

// ---- sliding-window attention: LDS-staged K/V (R5), swizzled sP ---------
// 1 block = (head, 64 queries); 4 waves x 16 queries; 64-key tiles.
__global__ __launch_bounds__(256, 4) void swa_kernel(
    const bf16_t* __restrict__ Qw, const bf16_t* __restrict__ Kw,
    const bf16_t* __restrict__ Vt, float* __restrict__ out) {
  __shared__ __align__(16) bf16_t sK[2][64 * 64];  // [key][d], swizzled chunks
  __shared__ __align__(16) bf16_t sV[2][64 * 64];  // [d][key], swizzled chunks
  __shared__ __align__(16) bf16_t sP[4 * 16 * 64]; // per-wave, swizzled chunks
  int h = blockIdx.y;
  int nb = blockIdx.x;
  int q0 = (((nb & 7) << 4) | (nb >> 3)) * 64;  // XCD-contiguous q-tiles
  int tid = threadIdx.x;
  int w = tid >> 6, lane = tid & 63, lm = lane & 15, qd = lane >> 4;
  int xb = q0 + w * 16;

  // Q B-frags (col=query=lm, k=d)
  int qoff = (h * S_LEN + xb + lm) * HD + qd * 8;
  bf16x8 aq0 = *reinterpret_cast<const bf16x8*>(Qw + qoff);
  bf16x8 aq1 = *reinterpret_cast<const bf16x8*>(Qw + qoff + 32);

  f32x4 o[4] = {};
  float lsum = 0.f;  // per-lane partial denom for query lm

  int y_begin = q0 - WIN; if (y_begin < 0) y_begin = 0;
  int y_end = q0 + 64 + WIN; if (y_end > S_LEN) y_end = S_LEN;
  int ntiles = (y_end - y_begin) >> 6;
  const bf16_t* Kh = Kw + h * S_LEN * HD;
  const bf16_t* Vh = Vt + h * HD * S_LEN;
  bf16_t* sPw = sP + w * 16 * 64;

  int srow = w * 8 + (lane >> 3);
  int sc8 = (lane & 7) ^ ((lane >> 3) & 7);
  int sx0 = lm & 7;

#define STAGE(y0, b)                                                    \
  {                                                                     \
    const bf16_t* kg = Kh + ((y0) + srow) * HD + sc8 * 8;               \
    gl2lds16(kg, &sK[b][w * 512]);                                      \
    gl2lds16(kg + 32 * HD, &sK[b][2048 + w * 512]);                     \
    const bf16_t* vg = Vh + srow * S_LEN + (y0) + sc8 * 8;              \
    gl2lds16(vg, &sV[b][w * 512]);                                      \
    gl2lds16(vg + 32 * S_LEN, &sV[b][2048 + w * 512]);                  \
  }

  STAGE(y_begin, 0);
  __syncthreads();

  for (int t = 0; t < ntiles; ++t) {
    int y0 = y_begin + t * 64;
    if (t + 1 < ntiles) STAGE(y0 + 64, (t + 1) & 1);
    int b = t & 1;
    // --- S^T = K.Q^T: rows=key (qd*4+r), cols=query (lm)
    f32x4 s[4] = {};
#pragma unroll
    for (int nt = 0; nt < 4; ++nt) {
      const bf16_t* kr = &sK[b][(nt * 16 + lm) * 64];
      bf16x8 b0 = *reinterpret_cast<const bf16x8*>(kr + (qd ^ sx0) * 8);
      bf16x8 b1 = *reinterpret_cast<const bf16x8*>(kr + ((qd + 4) ^ sx0) * 8);
      s[nt] = MFMA(b0, aq0, s[nt]);
      s[nt] = MFMA(b1, aq1, s[nt]);
    }
    // --- p = exp(s); mask only edge tiles; pack 4 keys -> one b64 write
    int dy = y0 - q0;
    bool edge = (dy > 192) || (dy < -192);
#pragma unroll
    for (int nt = 0; nt < 4; ++nt) {
      union { ushort4 u; bf16_t b[4]; } P;
#pragma unroll
      for (int r = 0; r < 4; ++r) {
        float pv;
        if (edge) {
          int dlt = (y0 + nt * 16 + qd * 4 + r) - (xb + lm);  // key - query
          pv = (dlt <= WIN && dlt >= -WIN) ? __expf(s[nt][r]) : 0.f;
        } else {
          pv = __expf(s[nt][r]);
        }
        lsum += pv;
        P.b[r] = __float2bfloat16(pv);
      }
      *reinterpret_cast<ushort4*>(
          sPw + lm * 64 + (((2 * nt + (qd >> 1)) ^ sx0) * 8) + (qd & 1) * 4) =
          P.u;
    }
    // --- P A-frags (row=query=lm, k=key): chunk qd / qd+4, same swizzle
    bf16x8 ap0 =
        *reinterpret_cast<const bf16x8*>(sPw + lm * 64 + ((qd ^ sx0) * 8));
    bf16x8 ap1 = *reinterpret_cast<const bf16x8*>(sPw + lm * 64 +
                                                  (((qd + 4) ^ sx0) * 8));
    // --- O += P.V (rows=query, cols=d)
#pragma unroll
    for (int nt = 0; nt < 4; ++nt) {
      const bf16_t* vr = &sV[b][(nt * 16 + lm) * 64];
      bf16x8 v0 = *reinterpret_cast<const bf16x8*>(vr + (qd ^ sx0) * 8);
      bf16x8 v1 = *reinterpret_cast<const bf16x8*>(vr + ((qd + 4) ^ sx0) * 8);
      o[nt] = MFMA(ap0, v0, o[nt]);
      o[nt] = MFMA(ap1, v1, o[nt]);
    }
    __syncthreads();  // drains prefetch + protects K/V buffers
  }
  // --- reduce lsum across the 4 qd-groups (query lives at lane lm)
  lsum += __shfl_xor(lsum, 16);
  lsum += __shfl_xor(lsum, 32);
  // --- normalize + store fp32; inv for row qd*4+r held at lane qd*4+r
#pragma unroll
  for (int r = 0; r < 4; ++r) {
    float inv = 1.f / __shfl(lsum, qd * 4 + r);
    int x = xb + qd * 4 + r;
#pragma unroll
    for (int nt = 0; nt < 4; ++nt)
      out[x * HID + h * HD + nt * 16 + lm] = o[nt][r] * inv;
  }
}

extern "C" void kernel_launch(void* const* d_in, const int* in_sizes, int n_in,
                              void* d_out, int out_size, void* d_ws, size_t ws_size,
                              hipStream_t stream) {
  const float* hs = (const float*)d_in[0];
  const float* Wq = (const float*)d_in[1];
  const float* bq = (const float*)d_in[2];
  const float* Wk = (const float*)d_in[3];
  const float* bk = (const float*)d_in[4];
  const float* Wv = (const float*)d_in[5];
  const float* bv = (const float*)d_in[6];
  float* out = (float*)d_out;

  const int NSH = S_LEN * HID;
  const int NW = 3 * HID * HID;
  bf16_t* p = (bf16_t*)d_ws;
  bf16_t* hb = p; p += NSH;
  bf16_t* Wt = p; p += NW;
  bf16_t* Qw = p; p += NSH;
  bf16_t* Kw = p; p += NSH;
  bf16_t* Vt = p; p += NSH;

  prep<<<dim3(6144 + 1728), dim3(256), 0, stream>>>(hs, hb, Wq, Wk, Wv, Wt);
  qkv_gemm<<<dim3(64, 9), dim3(512), 0, stream>>>(
      hb, Wt, bq, bk, bv, Qw, Kw, Vt);
  swa_kernel<<<dim3(128, 12), dim3(256), 0, stream>>>(Qw, Kw, Vt, out);
}

// Round 3
// 160.144 us; speedup vs baseline: 1.0992x; 1.0992x over previous
//
#include <hip/hip_runtime.h>
#include <hip/hip_bf16.h>

#define S_LEN 8192
#define HID 768
#define NH 12
#define HD 64
#define WIN 256

typedef __bf16 bf16x8 __attribute__((ext_vector_type(8)));
typedef float f32x4 __attribute__((ext_vector_type(4)));
using bf16_t = __hip_bfloat16;

#define MFMA(a, b, c) __builtin_amdgcn_mfma_f32_16x16x32_bf16(a, b, c, 0, 0, 0)

// async global->LDS, 16B/lane; LDS dest is wave-uniform base (+lane*16 in HW)
__device__ __forceinline__ void gl2lds16(const bf16_t* g, bf16_t* l) {
  __builtin_amdgcn_global_load_lds(
      (const __attribute__((address_space(1))) void*)g,
      (__attribute__((address_space(3))) void*)l, 16, 0, 0);
}

// ---- prep: fused hs fp32->bf16 convert + weight transpose ---------------
// blocks [0, 6144): convert; blocks [6144, 7872): transpose (24x24x3).
__global__ __launch_bounds__(256) void prep(const float* __restrict__ hs,
                                            bf16_t* __restrict__ hb,
                                            const float* __restrict__ Wq,
                                            const float* __restrict__ Wk,
                                            const float* __restrict__ Wv,
                                            bf16_t* __restrict__ Wt) {
  int bx = blockIdx.x;
  int tid = threadIdx.x;
  if (bx < 6144) {
    int i = (bx * 256 + tid) * 4;
    float4 v = *reinterpret_cast<const float4*>(hs + i);
    union { ushort4 u; bf16_t b[4]; } H;
    H.b[0] = __float2bfloat16(v.x);
    H.b[1] = __float2bfloat16(v.y);
    H.b[2] = __float2bfloat16(v.z);
    H.b[3] = __float2bfloat16(v.w);
    *reinterpret_cast<ushort4*>(hb + i) = H.u;
    return;
  }
  __shared__ float t[32][33];
  int b = bx - 6144;
  int z = b / 576;
  int r = b % 576;
  int n0 = (r / 24) * 32, k0 = (r % 24) * 32;
  const float* src = (z == 0) ? Wq : ((z == 1) ? Wk : Wv);
  int tx = tid & 31, ty = tid >> 5;  // 32 x 8
  for (int i = 0; i < 4; ++i)
    t[ty + i * 8][tx] = src[(k0 + ty + i * 8) * HID + n0 + tx];
  __syncthreads();
  bf16_t* dst = Wt + z * HID * HID;
  for (int i = 0; i < 4; ++i)
    dst[(n0 + ty + i * 8) * HID + k0 + tx] = __float2bfloat16(t[tx][ty + i * 8]);
}

// ---- fused QKV GEMM, 128x128 tile, BK=64, swizzled LDS ------------------
// R6-proven 2-phase double-buffer (45.4us): stage t+1 before compute t,
// ONE __syncthreads per K-step. R7's 8-phase port regressed (62us) -> reverted.
__global__ __launch_bounds__(256) void qkv_gemm(
    const bf16_t* __restrict__ hb, const bf16_t* __restrict__ Wt,
    const float* __restrict__ bq, const float* __restrict__ bk,
    const float* __restrict__ bv,
    bf16_t* __restrict__ Qw, bf16_t* __restrict__ Kw, bf16_t* __restrict__ Vt) {
  __shared__ __align__(16) bf16_t sA[2][128 * 64];
  __shared__ __align__(16) bf16_t sB[2][128 * 64];
  int m0 = blockIdx.x * 128;
  int zq = blockIdx.y / 6;
  int nn0 = (blockIdx.y % 6) * 128;
  int n0g = zq * HID + nn0;
  int tid = threadIdx.x;
  int w = tid >> 6, lane = tid & 63, lm = lane & 15, qd = lane >> 4;
  int wm = w & 1, wn = w >> 1;

  int srow = w * 8 + (lane >> 3);
  int sc8 = (lane & 7) ^ ((lane >> 3) & 7);
  const bf16_t* gA = hb + (m0 + srow) * HID + sc8 * 8;
  const bf16_t* gB = Wt + (n0g + srow) * HID + sc8 * 8;
  int sx0 = lm & 7;

#define QSTAGE(kk, bb)                                                     \
  {                                                                        \
    _Pragma("unroll") for (int u = 0; u < 4; ++u) {                        \
      gl2lds16(gA + (u * 32) * HID + (kk), sA[bb] + u * 2048 + w * 512);   \
      gl2lds16(gB + (u * 32) * HID + (kk), sB[bb] + u * 2048 + w * 512);   \
    }                                                                      \
  }

  QSTAGE(0, 0);
  __syncthreads();

  f32x4 acc[4][4] = {};
  for (int kt = 0; kt < 12; ++kt) {
    int b = kt & 1;
    if (kt < 11) QSTAGE((kt + 1) * 64, b ^ 1);
#pragma unroll
    for (int half = 0; half < 2; ++half) {
      int ca = (qd + 4 * half) ^ sx0;
      bf16x8 fa[4], fb[4];
#pragma unroll
      for (int i = 0; i < 4; ++i) {
        fa[i] = *reinterpret_cast<const bf16x8*>(
            sA[b] + (wm * 64 + i * 16 + lm) * 64 + ca * 8);
        fb[i] = *reinterpret_cast<const bf16x8*>(
            sB[b] + (wn * 64 + i * 16 + lm) * 64 + ca * 8);
      }
      if (zq == 2) {
#pragma unroll
        for (int i = 0; i < 4; ++i)
#pragma unroll
          for (int j = 0; j < 4; ++j)
            acc[i][j] = MFMA(fb[i], fa[j], acc[i][j]);  // C^T: rows=n
      } else {
#pragma unroll
        for (int i = 0; i < 4; ++i)
#pragma unroll
          for (int j = 0; j < 4; ++j)
            acc[i][j] = MFMA(fa[i], fb[j], acc[i][j]);  // rows=m
      }
    }
    __syncthreads();  // drains prefetch (RAW) + protects read buffer (WAR)
  }

  if (zq != 2) {
    const float* bias = zq ? bk : bq;
    bf16_t* dst = zq ? Kw : Qw;
    float scale = zq ? 1.0f : 0.125f;  // fold 1/sqrt(D) into Q
#pragma unroll
    for (int j = 0; j < 4; ++j) {
      int nl = nn0 + wn * 64 + j * 16 + lm;
      float bb = bias[nl];
      int h = nl >> 6, d = nl & 63;
#pragma unroll
      for (int i = 0; i < 4; ++i)
#pragma unroll
        for (int r = 0; r < 4; ++r) {
          int m = m0 + wm * 64 + i * 16 + qd * 4 + r;
          dst[(h * S_LEN + m) * HD + d] =
              __float2bfloat16((acc[i][j][r] + bb) * scale);
        }
    }
  } else {
#pragma unroll
    for (int i = 0; i < 4; ++i)
#pragma unroll
      for (int r = 0; r < 4; ++r) {
        int nl = nn0 + wn * 64 + i * 16 + qd * 4 + r;  // nl == h*64+d
        float bb = bv[nl];
#pragma unroll
        for (int j = 0; j < 4; ++j) {
          int m = m0 + wm * 64 + j * 16 + lm;
          Vt[nl * S_LEN + m] = __float2bfloat16(acc[i][j][r] + bb);
        }
      }
  }
}

// ---- sliding-window attention, R8: 32 queries/wave (128/block) ----------
// K/V fragment reads + staging shared across both 16-query groups:
// 20 ds_read_b128 / 32 MFMA per tile (was 18/16); staging per query halved
// (10 tiles per 128 q vs 9 per 64 q). LDS 48KB -> 3 blocks/CU; grid
// 64x12 = 768 = exactly 3/CU x 256 CUs -> one full round, no tail.
__global__ __launch_bounds__(256, 3) void swa_kernel(
    const bf16_t* __restrict__ Qw, const bf16_t* __restrict__ Kw,
    const bf16_t* __restrict__ Vt, float* __restrict__ out) {
  __shared__ __align__(16) bf16_t sK[2][64 * 64];   // [key][d], swizzled chunks
  __shared__ __align__(16) bf16_t sV[2][64 * 64];   // [d][key], swizzled chunks
  __shared__ __align__(16) bf16_t sP[4 * 32 * 64];  // per-wave, swizzled chunks
  int h = blockIdx.y;
  int nb = blockIdx.x;                              // [0,64)
  int q0 = (((nb & 7) << 3) | (nb >> 3)) * 128;     // XCD-contiguous q-tiles
  int tid = threadIdx.x;
  int w = tid >> 6, lane = tid & 63, lm = lane & 15, qd = lane >> 4;
  int xb = q0 + w * 32;

  // Q B-frags for both 16-query groups (col=query=lm, k=d)
  int qoff = (h * S_LEN + xb + lm) * HD + qd * 8;
  bf16x8 aq00 = *reinterpret_cast<const bf16x8*>(Qw + qoff);
  bf16x8 aq01 = *reinterpret_cast<const bf16x8*>(Qw + qoff + 32);
  bf16x8 aq10 = *reinterpret_cast<const bf16x8*>(Qw + qoff + 16 * HD);
  bf16x8 aq11 = *reinterpret_cast<const bf16x8*>(Qw + qoff + 16 * HD + 32);

  f32x4 o0[4] = {}, o1[4] = {};
  float lsum0 = 0.f, lsum1 = 0.f;  // per-lane partial denoms

  int y_begin = q0 - WIN; if (y_begin < 0) y_begin = 0;
  int y_end = q0 + 128 + WIN; if (y_end > S_LEN) y_end = S_LEN;
  int ntiles = (y_end - y_begin) >> 6;
  const bf16_t* Kh = Kw + h * S_LEN * HD;
  const bf16_t* Vh = Vt + h * HD * S_LEN;
  bf16_t* sPw = sP + w * 32 * 64;

  int srow = w * 8 + (lane >> 3);
  int sc8 = (lane & 7) ^ ((lane >> 3) & 7);
  int sx0 = lm & 7;

#define STAGE(y0, b)                                                    \
  {                                                                     \
    const bf16_t* kg = Kh + ((y0) + srow) * HD + sc8 * 8;               \
    gl2lds16(kg, &sK[b][w * 512]);                                      \
    gl2lds16(kg + 32 * HD, &sK[b][2048 + w * 512]);                     \
    const bf16_t* vg = Vh + srow * S_LEN + (y0) + sc8 * 8;              \
    gl2lds16(vg, &sV[b][w * 512]);                                      \
    gl2lds16(vg + 32 * S_LEN, &sV[b][2048 + w * 512]);                  \
  }

  STAGE(y_begin, 0);
  __syncthreads();

  for (int t = 0; t < ntiles; ++t) {
    int y0 = y_begin + t * 64;
    if (t + 1 < ntiles) STAGE(y0 + 64, (t + 1) & 1);
    int b = t & 1;
    // --- S^T = K.Q^T: rows=key (qd*4+r), cols=query (lm); K-frags shared
    f32x4 s0[4] = {}, s1[4] = {};
#pragma unroll
    for (int nt = 0; nt < 4; ++nt) {
      const bf16_t* kr = &sK[b][(nt * 16 + lm) * 64];
      bf16x8 b0 = *reinterpret_cast<const bf16x8*>(kr + (qd ^ sx0) * 8);
      bf16x8 b1 = *reinterpret_cast<const bf16x8*>(kr + ((qd + 4) ^ sx0) * 8);
      s0[nt] = MFMA(b0, aq00, s0[nt]);
      s0[nt] = MFMA(b1, aq01, s0[nt]);
      s1[nt] = MFMA(b0, aq10, s1[nt]);
      s1[nt] = MFMA(b1, aq11, s1[nt]);
    }
    // --- p = exp(s); mask only edge tiles (per-wave query span = 32)
    int dyw = y0 - xb;
    bool edge = (dyw > 193) || (dyw < -225);
#pragma unroll
    for (int g = 0; g < 2; ++g) {
      const f32x4* sg = g ? s1 : s0;
      float lacc = 0.f;
#pragma unroll
      for (int nt = 0; nt < 4; ++nt) {
        union { ushort4 u; bf16_t b[4]; } P;
#pragma unroll
        for (int r = 0; r < 4; ++r) {
          float pv;
          if (edge) {
            int dlt = (y0 + nt * 16 + qd * 4 + r) - (xb + g * 16 + lm);
            pv = (dlt <= WIN && dlt >= -WIN) ? __expf(sg[nt][r]) : 0.f;
          } else {
            pv = __expf(sg[nt][r]);
          }
          lacc += pv;
          P.b[r] = __float2bfloat16(pv);
        }
        *reinterpret_cast<ushort4*>(
            sPw + (g * 16 + lm) * 64 +
            (((2 * nt + (qd >> 1)) ^ sx0) * 8) + (qd & 1) * 4) = P.u;
      }
      if (g) lsum1 += lacc; else lsum0 += lacc;
    }
    // --- P A-frags (row=query=lm within group, k=key)
    bf16x8 ap00 =
        *reinterpret_cast<const bf16x8*>(sPw + lm * 64 + ((qd ^ sx0) * 8));
    bf16x8 ap01 = *reinterpret_cast<const bf16x8*>(sPw + lm * 64 +
                                                   (((qd + 4) ^ sx0) * 8));
    bf16x8 ap10 = *reinterpret_cast<const bf16x8*>(sPw + (16 + lm) * 64 +
                                                   ((qd ^ sx0) * 8));
    bf16x8 ap11 = *reinterpret_cast<const bf16x8*>(sPw + (16 + lm) * 64 +
                                                   (((qd + 4) ^ sx0) * 8));
    // --- O += P.V (rows=query, cols=d); V-frags shared across groups
#pragma unroll
    for (int nt = 0; nt < 4; ++nt) {
      const bf16_t* vr = &sV[b][(nt * 16 + lm) * 64];
      bf16x8 v0 = *reinterpret_cast<const bf16x8*>(vr + (qd ^ sx0) * 8);
      bf16x8 v1 = *reinterpret_cast<const bf16x8*>(vr + ((qd + 4) ^ sx0) * 8);
      o0[nt] = MFMA(ap00, v0, o0[nt]);
      o0[nt] = MFMA(ap01, v1, o0[nt]);
      o1[nt] = MFMA(ap10, v0, o1[nt]);
      o1[nt] = MFMA(ap11, v1, o1[nt]);
    }
    __syncthreads();  // drains prefetch + protects K/V buffers
  }
  // --- reduce lsum across the 4 qd-groups (query lives at lane lm)
  lsum0 += __shfl_xor(lsum0, 16);
  lsum0 += __shfl_xor(lsum0, 32);
  lsum1 += __shfl_xor(lsum1, 16);
  lsum1 += __shfl_xor(lsum1, 32);
  // --- normalize + store fp32; inv for row qd*4+r held at lane qd*4+r
#pragma unroll
  for (int r = 0; r < 4; ++r) {
    float inv0 = 1.f / __shfl(lsum0, qd * 4 + r);
    int x0 = xb + qd * 4 + r;
#pragma unroll
    for (int nt = 0; nt < 4; ++nt)
      out[x0 * HID + h * HD + nt * 16 + lm] = o0[nt][r] * inv0;
    float inv1 = 1.f / __shfl(lsum1, qd * 4 + r);
    int x1 = xb + 16 + qd * 4 + r;
#pragma unroll
    for (int nt = 0; nt < 4; ++nt)
      out[x1 * HID + h * HD + nt * 16 + lm] = o1[nt][r] * inv1;
  }
}

extern "C" void kernel_launch(void* const* d_in, const int* in_sizes, int n_in,
                              void* d_out, int out_size, void* d_ws, size_t ws_size,
                              hipStream_t stream) {
  const float* hs = (const float*)d_in[0];
  const float* Wq = (const float*)d_in[1];
  const float* bq = (const float*)d_in[2];
  const float* Wk = (const float*)d_in[3];
  const float* bk = (const float*)d_in[4];
  const float* Wv = (const float*)d_in[5];
  const float* bv = (const float*)d_in[6];
  float* out = (float*)d_out;

  const int NSH = S_LEN * HID;
  const int NW = 3 * HID * HID;
  bf16_t* p = (bf16_t*)d_ws;
  bf16_t* hb = p; p += NSH;
  bf16_t* Wt = p; p += NW;
  bf16_t* Qw = p; p += NSH;
  bf16_t* Kw = p; p += NSH;
  bf16_t* Vt = p; p += NSH;

  prep<<<dim3(6144 + 1728), dim3(256), 0, stream>>>(hs, hb, Wq, Wk, Wv, Wt);
  qkv_gemm<<<dim3(64, 18), dim3(256), 0, stream>>>(
      hb, Wt, bq, bk, bv, Qw, Kw, Vt);
  swa_kernel<<<dim3(64, 12), dim3(256), 0, stream>>>(Qw, Kw, Vt, out);
}

// Round 4
// 157.914 us; speedup vs baseline: 1.1147x; 1.0141x over previous
//
#include <hip/hip_runtime.h>
#include <hip/hip_bf16.h>

#define S_LEN 8192
#define HID 768
#define NH 12
#define HD 64
#define WIN 256

typedef __bf16 bf16x8 __attribute__((ext_vector_type(8)));
typedef float f32x4 __attribute__((ext_vector_type(4)));
using bf16_t = __hip_bfloat16;

#define MFMA(a, b, c) __builtin_amdgcn_mfma_f32_16x16x32_bf16(a, b, c, 0, 0, 0)

// async global->LDS, 16B/lane; LDS dest is wave-uniform base (+lane*16 in HW)
__device__ __forceinline__ void gl2lds16(const bf16_t* g, bf16_t* l) {
  __builtin_amdgcn_global_load_lds(
      (const __attribute__((address_space(1))) void*)g,
      (__attribute__((address_space(3))) void*)l, 16, 0, 0);
}

// ---- prep: fused hs fp32->bf16 convert + weight transpose ---------------
// blocks [0, 6144): convert; blocks [6144, 7872): transpose (24x24x3).
__global__ __launch_bounds__(256) void prep(const float* __restrict__ hs,
                                            bf16_t* __restrict__ hb,
                                            const float* __restrict__ Wq,
                                            const float* __restrict__ Wk,
                                            const float* __restrict__ Wv,
                                            bf16_t* __restrict__ Wt) {
  int bx = blockIdx.x;
  int tid = threadIdx.x;
  if (bx < 6144) {
    int i = (bx * 256 + tid) * 4;
    float4 v = *reinterpret_cast<const float4*>(hs + i);
    union { ushort4 u; bf16_t b[4]; } H;
    H.b[0] = __float2bfloat16(v.x);
    H.b[1] = __float2bfloat16(v.y);
    H.b[2] = __float2bfloat16(v.z);
    H.b[3] = __float2bfloat16(v.w);
    *reinterpret_cast<ushort4*>(hb + i) = H.u;
    return;
  }
  __shared__ float t[32][33];
  int b = bx - 6144;
  int z = b / 576;
  int r = b % 576;
  int n0 = (r / 24) * 32, k0 = (r % 24) * 32;
  const float* src = (z == 0) ? Wq : ((z == 1) ? Wk : Wv);
  int tx = tid & 31, ty = tid >> 5;  // 32 x 8
  for (int i = 0; i < 4; ++i)
    t[ty + i * 8][tx] = src[(k0 + ty + i * 8) * HID + n0 + tx];
  __syncthreads();
  bf16_t* dst = Wt + z * HID * HID;
  for (int i = 0; i < 4; ++i)
    dst[(n0 + ty + i * 8) * HID + k0 + tx] = __float2bfloat16(t[tx][ty + i * 8]);
}

// ---- fused QKV GEMM, 128x128 tile, BK=64, swizzled LDS ------------------
// R6-proven 2-phase double-buffer. R9: XCD-aware (m,n) remap (T1): each XCD
// owns 8 contiguous m-tiles (1.6MB A slice, L2-resident) swept across all
// 18 n-steps -> A fetched ~once from HBM instead of 2.2x, and most A loads
// become ~200cy L2 hits, shrinking the per-K-step vmcnt(0) drain stall.
__global__ __launch_bounds__(256) void qkv_gemm(
    const bf16_t* __restrict__ hb, const bf16_t* __restrict__ Wt,
    const float* __restrict__ bq, const float* __restrict__ bk,
    const float* __restrict__ bv,
    bf16_t* __restrict__ Qw, bf16_t* __restrict__ Kw, bf16_t* __restrict__ Vt) {
  __shared__ __align__(16) bf16_t sA[2][128 * 64];
  __shared__ __align__(16) bf16_t sB[2][128 * 64];
  // bijective remap over 1152 blocks: b -> (xcd, mloc, n-step)
  int bl = blockIdx.y * 64 + blockIdx.x;
  int xcd = bl & 7;
  int j = bl >> 3;               // [0,144)
  int m0 = (xcd * 8 + (j & 7)) * 128;
  int rest = j >> 3;             // [0,18)
  int zq = rest / 6;
  int nn0 = (rest % 6) * 128;
  int n0g = zq * HID + nn0;
  int tid = threadIdx.x;
  int w = tid >> 6, lane = tid & 63, lm = lane & 15, qd = lane >> 4;
  int wm = w & 1, wn = w >> 1;

  int srow = w * 8 + (lane >> 3);
  int sc8 = (lane & 7) ^ ((lane >> 3) & 7);
  const bf16_t* gA = hb + (m0 + srow) * HID + sc8 * 8;
  const bf16_t* gB = Wt + (n0g + srow) * HID + sc8 * 8;
  int sx0 = lm & 7;

#define QSTAGE(kk, bb)                                                     \
  {                                                                        \
    _Pragma("unroll") for (int u = 0; u < 4; ++u) {                        \
      gl2lds16(gA + (u * 32) * HID + (kk), sA[bb] + u * 2048 + w * 512);   \
      gl2lds16(gB + (u * 32) * HID + (kk), sB[bb] + u * 2048 + w * 512);   \
    }                                                                      \
  }

  QSTAGE(0, 0);
  __syncthreads();

  f32x4 acc[4][4] = {};
  for (int kt = 0; kt < 12; ++kt) {
    int b = kt & 1;
    if (kt < 11) QSTAGE((kt + 1) * 64, b ^ 1);
#pragma unroll
    for (int half = 0; half < 2; ++half) {
      int ca = (qd + 4 * half) ^ sx0;
      bf16x8 fa[4], fb[4];
#pragma unroll
      for (int i = 0; i < 4; ++i) {
        fa[i] = *reinterpret_cast<const bf16x8*>(
            sA[b] + (wm * 64 + i * 16 + lm) * 64 + ca * 8);
        fb[i] = *reinterpret_cast<const bf16x8*>(
            sB[b] + (wn * 64 + i * 16 + lm) * 64 + ca * 8);
      }
      if (zq == 2) {
#pragma unroll
        for (int i = 0; i < 4; ++i)
#pragma unroll
          for (int j2 = 0; j2 < 4; ++j2)
            acc[i][j2] = MFMA(fb[i], fa[j2], acc[i][j2]);  // C^T: rows=n
      } else {
#pragma unroll
        for (int i = 0; i < 4; ++i)
#pragma unroll
          for (int j2 = 0; j2 < 4; ++j2)
            acc[i][j2] = MFMA(fa[i], fb[j2], acc[i][j2]);  // rows=m
      }
    }
    __syncthreads();  // drains prefetch (RAW) + protects read buffer (WAR)
  }

  if (zq != 2) {
    const float* bias = zq ? bk : bq;
    bf16_t* dst = zq ? Kw : Qw;
    float scale = zq ? 1.0f : 0.125f;  // fold 1/sqrt(D) into Q
#pragma unroll
    for (int j2 = 0; j2 < 4; ++j2) {
      int nl = nn0 + wn * 64 + j2 * 16 + lm;
      float bb = bias[nl];
      int h = nl >> 6, d = nl & 63;
#pragma unroll
      for (int i = 0; i < 4; ++i)
#pragma unroll
        for (int r = 0; r < 4; ++r) {
          int m = m0 + wm * 64 + i * 16 + qd * 4 + r;
          dst[(h * S_LEN + m) * HD + d] =
              __float2bfloat16((acc[i][j2][r] + bb) * scale);
        }
    }
  } else {
#pragma unroll
    for (int i = 0; i < 4; ++i)
#pragma unroll
      for (int r = 0; r < 4; ++r) {
        int nl = nn0 + wn * 64 + i * 16 + qd * 4 + r;  // nl == h*64+d
        float bb = bv[nl];
#pragma unroll
        for (int j2 = 0; j2 < 4; ++j2) {
          int m = m0 + wm * 64 + j2 * 16 + lm;
          Vt[nl * S_LEN + m] = __float2bfloat16(acc[i][j2][r] + bb);
        }
      }
  }
}

// ---- sliding-window attention, R8: 32 queries/wave (128/block) ----------
// K/V fragment reads + staging shared across both 16-query groups.
// LDS 48KB -> 3 blocks/CU; grid 64x12 = 768 = 3/CU x 256 CUs, no tail.
__global__ __launch_bounds__(256, 3) void swa_kernel(
    const bf16_t* __restrict__ Qw, const bf16_t* __restrict__ Kw,
    const bf16_t* __restrict__ Vt, float* __restrict__ out) {
  __shared__ __align__(16) bf16_t sK[2][64 * 64];   // [key][d], swizzled chunks
  __shared__ __align__(16) bf16_t sV[2][64 * 64];   // [d][key], swizzled chunks
  __shared__ __align__(16) bf16_t sP[4 * 32 * 64];  // per-wave, swizzled chunks
  int h = blockIdx.y;
  int nb = blockIdx.x;                              // [0,64)
  int q0 = (((nb & 7) << 3) | (nb >> 3)) * 128;     // XCD-contiguous q-tiles
  int tid = threadIdx.x;
  int w = tid >> 6, lane = tid & 63, lm = lane & 15, qd = lane >> 4;
  int xb = q0 + w * 32;

  // Q B-frags for both 16-query groups (col=query=lm, k=d)
  int qoff = (h * S_LEN + xb + lm) * HD + qd * 8;
  bf16x8 aq00 = *reinterpret_cast<const bf16x8*>(Qw + qoff);
  bf16x8 aq01 = *reinterpret_cast<const bf16x8*>(Qw + qoff + 32);
  bf16x8 aq10 = *reinterpret_cast<const bf16x8*>(Qw + qoff + 16 * HD);
  bf16x8 aq11 = *reinterpret_cast<const bf16x8*>(Qw + qoff + 16 * HD + 32);

  f32x4 o0[4] = {}, o1[4] = {};
  float lsum0 = 0.f, lsum1 = 0.f;  // per-lane partial denoms

  int y_begin = q0 - WIN; if (y_begin < 0) y_begin = 0;
  int y_end = q0 + 128 + WIN; if (y_end > S_LEN) y_end = S_LEN;
  int ntiles = (y_end - y_begin) >> 6;
  const bf16_t* Kh = Kw + h * S_LEN * HD;
  const bf16_t* Vh = Vt + h * HD * S_LEN;
  bf16_t* sPw = sP + w * 32 * 64;

  int srow = w * 8 + (lane >> 3);
  int sc8 = (lane & 7) ^ ((lane >> 3) & 7);
  int sx0 = lm & 7;

#define STAGE(y0, b)                                                    \
  {                                                                     \
    const bf16_t* kg = Kh + ((y0) + srow) * HD + sc8 * 8;               \
    gl2lds16(kg, &sK[b][w * 512]);                                      \
    gl2lds16(kg + 32 * HD, &sK[b][2048 + w * 512]);                     \
    const bf16_t* vg = Vh + srow * S_LEN + (y0) + sc8 * 8;              \
    gl2lds16(vg, &sV[b][w * 512]);                                      \
    gl2lds16(vg + 32 * S_LEN, &sV[b][2048 + w * 512]);                  \
  }

  STAGE(y_begin, 0);
  __syncthreads();

  for (int t = 0; t < ntiles; ++t) {
    int y0 = y_begin + t * 64;
    if (t + 1 < ntiles) STAGE(y0 + 64, (t + 1) & 1);
    int b = t & 1;
    // --- S^T = K.Q^T: rows=key (qd*4+r), cols=query (lm); K-frags shared
    f32x4 s0[4] = {}, s1[4] = {};
#pragma unroll
    for (int nt = 0; nt < 4; ++nt) {
      const bf16_t* kr = &sK[b][(nt * 16 + lm) * 64];
      bf16x8 b0 = *reinterpret_cast<const bf16x8*>(kr + (qd ^ sx0) * 8);
      bf16x8 b1 = *reinterpret_cast<const bf16x8*>(kr + ((qd + 4) ^ sx0) * 8);
      s0[nt] = MFMA(b0, aq00, s0[nt]);
      s0[nt] = MFMA(b1, aq01, s0[nt]);
      s1[nt] = MFMA(b0, aq10, s1[nt]);
      s1[nt] = MFMA(b1, aq11, s1[nt]);
    }
    // --- p = exp(s); mask only edge tiles (per-wave query span = 32)
    int dyw = y0 - xb;
    bool edge = (dyw > 193) || (dyw < -225);
#pragma unroll
    for (int g = 0; g < 2; ++g) {
      const f32x4* sg = g ? s1 : s0;
      float lacc = 0.f;
#pragma unroll
      for (int nt = 0; nt < 4; ++nt) {
        union { ushort4 u; bf16_t b[4]; } P;
#pragma unroll
        for (int r = 0; r < 4; ++r) {
          float pv;
          if (edge) {
            int dlt = (y0 + nt * 16 + qd * 4 + r) - (xb + g * 16 + lm);
            pv = (dlt <= WIN && dlt >= -WIN) ? __expf(sg[nt][r]) : 0.f;
          } else {
            pv = __expf(sg[nt][r]);
          }
          lacc += pv;
          P.b[r] = __float2bfloat16(pv);
        }
        *reinterpret_cast<ushort4*>(
            sPw + (g * 16 + lm) * 64 +
            (((2 * nt + (qd >> 1)) ^ sx0) * 8) + (qd & 1) * 4) = P.u;
      }
      if (g) lsum1 += lacc; else lsum0 += lacc;
    }
    // --- P A-frags (row=query=lm within group, k=key)
    bf16x8 ap00 =
        *reinterpret_cast<const bf16x8*>(sPw + lm * 64 + ((qd ^ sx0) * 8));
    bf16x8 ap01 = *reinterpret_cast<const bf16x8*>(sPw + lm * 64 +
                                                   (((qd + 4) ^ sx0) * 8));
    bf16x8 ap10 = *reinterpret_cast<const bf16x8*>(sPw + (16 + lm) * 64 +
                                                   ((qd ^ sx0) * 8));
    bf16x8 ap11 = *reinterpret_cast<const bf16x8*>(sPw + (16 + lm) * 64 +
                                                   (((qd + 4) ^ sx0) * 8));
    // --- O += P.V (rows=query, cols=d); V-frags shared across groups
#pragma unroll
    for (int nt = 0; nt < 4; ++nt) {
      const bf16_t* vr = &sV[b][(nt * 16 + lm) * 64];
      bf16x8 v0 = *reinterpret_cast<const bf16x8*>(vr + (qd ^ sx0) * 8);
      bf16x8 v1 = *reinterpret_cast<const bf16x8*>(vr + ((qd + 4) ^ sx0) * 8);
      o0[nt] = MFMA(ap00, v0, o0[nt]);
      o0[nt] = MFMA(ap01, v1, o0[nt]);
      o1[nt] = MFMA(ap10, v0, o1[nt]);
      o1[nt] = MFMA(ap11, v1, o1[nt]);
    }
    __syncthreads();  // drains prefetch + protects K/V buffers
  }
  // --- reduce lsum across the 4 qd-groups (query lives at lane lm)
  lsum0 += __shfl_xor(lsum0, 16);
  lsum0 += __shfl_xor(lsum0, 32);
  lsum1 += __shfl_xor(lsum1, 16);
  lsum1 += __shfl_xor(lsum1, 32);
  // --- normalize + store fp32; inv for row qd*4+r held at lane qd*4+r
#pragma unroll
  for (int r = 0; r < 4; ++r) {
    float inv0 = 1.f / __shfl(lsum0, qd * 4 + r);
    int x0 = xb + qd * 4 + r;
#pragma unroll
    for (int nt = 0; nt < 4; ++nt)
      out[x0 * HID + h * HD + nt * 16 + lm] = o0[nt][r] * inv0;
    float inv1 = 1.f / __shfl(lsum1, qd * 4 + r);
    int x1 = xb + 16 + qd * 4 + r;
#pragma unroll
    for (int nt = 0; nt < 4; ++nt)
      out[x1 * HID + h * HD + nt * 16 + lm] = o1[nt][r] * inv1;
  }
}

extern "C" void kernel_launch(void* const* d_in, const int* in_sizes, int n_in,
                              void* d_out, int out_size, void* d_ws, size_t ws_size,
                              hipStream_t stream) {
  const float* hs = (const float*)d_in[0];
  const float* Wq = (const float*)d_in[1];
  const float* bq = (const float*)d_in[2];
  const float* Wk = (const float*)d_in[3];
  const float* bk = (const float*)d_in[4];
  const float* Wv = (const float*)d_in[5];
  const float* bv = (const float*)d_in[6];
  float* out = (float*)d_out;

  const int NSH = S_LEN * HID;
  const int NW = 3 * HID * HID;
  bf16_t* p = (bf16_t*)d_ws;
  bf16_t* hb = p; p += NSH;
  bf16_t* Wt = p; p += NW;
  bf16_t* Qw = p; p += NSH;
  bf16_t* Kw = p; p += NSH;
  bf16_t* Vt = p; p += NSH;

  prep<<<dim3(6144 + 1728), dim3(256), 0, stream>>>(hs, hb, Wq, Wk, Wv, Wt);
  qkv_gemm<<<dim3(64, 18), dim3(256), 0, stream>>>(
      hb, Wt, bq, bk, bv, Qw, Kw, Vt);
  swa_kernel<<<dim3(64, 12), dim3(256), 0, stream>>>(Qw, Kw, Vt, out);
}